// Round 1
// baseline (410.435 us; speedup 1.0000x reference)
//
#include <hip/hip_runtime.h>
#include <math.h>

#define B_ 16
#define H_ 224
#define W_ 224
#define HP_ 226
#define WP_ 226
#define CIN_ 3
#define COUT_ 64
#define NPIX_ (B_ * H_ * W_)      /* 802816 */
#define NPAD_ (B_ * HP_ * WP_)    /* 817216 */
#define NBLK_ (NPIX_ / 256)       /* 3136 */
#define MAXNORM_ 0.999f
#define MINN_ 1e-7f
#define TCL_ (1.0f - 1e-5f)
#define LCLAMP_ 3.8002012f        /* atanh(0.999) */
#define BN_EPS_ 1e-5f
#define NF_ ((float)NPIX_)

// ---------------------------------------------------------------------------
// K0: x (NCHW f32) -> u0p (padded NHWC4): u0 = logmap0(projx(x)) per pixel,
// zero halo ring (SAME padding happens in tangent space). ws is re-poisoned
// every launch, so the halo must be rewritten every call.
// ---------------------------------------------------------------------------
__global__ void k0_transform(const float* __restrict__ x, float4* __restrict__ u0p) {
  int idx = blockIdx.x * 256 + threadIdx.x;
  if (idx >= NPAD_) return;
  int b = idx / (HP_ * WP_);
  int r = idx % (HP_ * WP_);
  int yp = r / WP_, xp = r % WP_;
  float4 o = make_float4(0.f, 0.f, 0.f, 0.f);
  if (yp >= 1 && yp <= H_ && xp >= 1 && xp <= W_) {
    const float* xb = x + (size_t)b * (CIN_ * H_ * W_) + (size_t)(yp - 1) * W_ + (xp - 1);
    float v0 = xb[0];
    float v1 = xb[H_ * W_];
    float v2 = xb[2 * H_ * W_];
    // projx
    float n = sqrtf(fmaf(v0, v0, fmaf(v1, v1, v2 * v2)));
    float ncl = fmaxf(n, MINN_);
    float s = fminf(1.0f, MAXNORM_ / ncl);
    float p0 = v0 * s, p1 = v1 * s, p2 = v2 * s;
    // logmap0
    float np_ = fmaxf(sqrtf(fmaf(p0, p0, fmaf(p1, p1, p2 * p2))), MINN_);
    float t = fminf(np_, TCL_);
    float f = atanhf(t) / np_;
    o.x = p0 * f; o.y = p1 * f; o.z = p2 * f;
  }
  u0p[idx] = o;
}

// ---------------------------------------------------------------------------
// Shared conv: one thread = one output pixel, all 64 output channels in VGPRs.
// Weight indices are wave-uniform -> scalar (s_load) weight fetches; the FMA
// takes the weight as its single allowed SGPR operand. Then fuse
// logmap0(projx(expmap0(t))) == t * min(1, L/||t||).
// ---------------------------------------------------------------------------
__device__ __forceinline__ void conv_clamp(const float4* __restrict__ u0p,
                                           const float* __restrict__ wgt,
                                           const float* __restrict__ bias,
                                           int pix, float acc[COUT_]) {
  int b = pix / (H_ * W_);
  int r = pix % (H_ * W_);
  int y = r / W_, x = r % W_;
  const float4* base = u0p + ((size_t)b * HP_ + y) * WP_ + x;
#pragma unroll
  for (int c = 0; c < COUT_; c++) acc[c] = bias[c];
#pragma unroll
  for (int dy = 0; dy < 3; dy++) {
#pragma unroll
    for (int dx = 0; dx < 3; dx++) {
      float4 in = base[dy * WP_ + dx];
      const float* wp = wgt + (size_t)((dy * 3 + dx) * 3) * COUT_;  // HWIO layout
#pragma unroll
      for (int c = 0; c < COUT_; c++) acc[c] = fmaf(in.x, wp[c], acc[c]);
#pragma unroll
      for (int c = 0; c < COUT_; c++) acc[c] = fmaf(in.y, wp[COUT_ + c], acc[c]);
#pragma unroll
      for (int c = 0; c < COUT_; c++) acc[c] = fmaf(in.z, wp[2 * COUT_ + c], acc[c]);
    }
  }
  float n2 = 0.f;
#pragma unroll
  for (int c = 0; c < COUT_; c++) n2 = fmaf(acc[c], acc[c], n2);
  float n = sqrtf(n2);
  float s = (n > LCLAMP_) ? (LCLAMP_ / n) : 1.0f;
#pragma unroll
  for (int c = 0; c < COUT_; c++) acc[c] *= s;
}

// ---------------------------------------------------------------------------
// K1: conv + clamp, then per-wave channel-ownership butterfly (all-static
// register indices, no scratch spill): after 6 xor-fold steps lane l holds the
// wave total for channel l (sum and sumsq). Block-combine in LDS, write one
// 128-float partial row per block.
// ---------------------------------------------------------------------------
__global__ void k1_stats(const float4* __restrict__ u0p, const float* __restrict__ wgt,
                         const float* __restrict__ bias, float* __restrict__ partials) {
  int pix = blockIdx.x * 256 + threadIdx.x;
  float s[COUT_];
  conv_clamp(u0p, wgt, bias, pix, s);
  float q[COUT_];
#pragma unroll
  for (int c = 0; c < COUT_; c++) q[c] = s[c] * s[c];
  int lane = threadIdx.x & 63;
#pragma unroll
  for (int k = 0; k < 6; k++) {
    int bit = (lane >> k) & 1;
#pragma unroll
    for (int j = 0; j < (64 >> k); j += 2) {
      float a0 = s[j]     + __shfl_xor(s[j],     1 << k, 64);
      float a1 = s[j + 1] + __shfl_xor(s[j + 1], 1 << k, 64);
      s[j >> 1] = bit ? a1 : a0;
      float b0 = q[j]     + __shfl_xor(q[j],     1 << k, 64);
      float b1 = q[j + 1] + __shfl_xor(q[j + 1], 1 << k, 64);
      q[j >> 1] = bit ? b1 : b0;
    }
  }
  __shared__ float red[512];
  int wid = threadIdx.x >> 6;
  red[wid * 64 + lane] = s[0];
  red[256 + wid * 64 + lane] = q[0];
  __syncthreads();
  int tid = threadIdx.x;
  if (tid < 128) {
    int off = (tid < 64) ? 0 : (256 - 64);
    float tot = red[off + tid] + red[off + tid + 64] + red[off + tid + 128] + red[off + tid + 192];
    // layout: partials[blk*128 + c] = sum_c  ;  partials[blk*128 + 64 + c] = sumsq_c
    // (tid<64 -> index tid ; tid>=64 -> index tid)  [off shifts the wave-bank]
    partials[(size_t)blockIdx.x * 128 + tid] = tot;
  }
}

// ---------------------------------------------------------------------------
// K2: reduce 3136 x 128 partials -> mean[c], rstd*gamma[c]. One 1024-thread
// block, float4 chunked 32-way so ~8 loads are in flight per thread.
// ---------------------------------------------------------------------------
__global__ void k2_finalize(const float* __restrict__ partials, const float* __restrict__ gamma,
                            float* __restrict__ stats) {
  __shared__ float lds[32 * 128 + 128];
  int tid = threadIdx.x;  // 1024 threads
  int chunk = tid >> 5, qi = tid & 31;
  const float4* p4 = (const float4*)partials;
  float4 a = make_float4(0.f, 0.f, 0.f, 0.f);
#pragma unroll 7
  for (int i = chunk; i < NBLK_; i += 32) {
    float4 v = p4[(size_t)i * 32 + qi];
    a.x += v.x; a.y += v.y; a.z += v.z; a.w += v.w;
  }
  lds[chunk * 128 + qi * 4 + 0] = a.x;
  lds[chunk * 128 + qi * 4 + 1] = a.y;
  lds[chunk * 128 + qi * 4 + 2] = a.z;
  lds[chunk * 128 + qi * 4 + 3] = a.w;
  __syncthreads();
  if (tid < 128) {
    float tot = 0.f;
#pragma unroll
    for (int ch = 0; ch < 32; ch++) tot += lds[ch * 128 + tid];
    lds[32 * 128 + tid] = tot;
  }
  __syncthreads();
  if (tid < 64) {
    float mean = lds[32 * 128 + tid] / NF_;
    float msq  = lds[32 * 128 + 64 + tid] / NF_;
    float var = msq - mean * mean;            // jnp.var (ddof=0)
    float rstdg = gamma[tid] / sqrtf(var + BN_EPS_);
    stats[tid] = mean;
    stats[64 + tid] = rstdg;
  }
}

// ---------------------------------------------------------------------------
// K3: conv + clamp + BN affine + clamp + ReLU + real expmap0 (+projx) + store.
// ---------------------------------------------------------------------------
__global__ void k3_final(const float4* __restrict__ u0p, const float* __restrict__ wgt,
                         const float* __restrict__ bias, const float* __restrict__ stats,
                         const float* __restrict__ beta, float* __restrict__ out) {
  int pix = blockIdx.x * 256 + threadIdx.x;
  float acc[COUT_];
  conv_clamp(u0p, wgt, bias, pix, acc);
  // BN:  v = (u2 - mean) * (rstd*gamma) + beta    (stats indices wave-uniform)
  float nv2 = 0.f;
#pragma unroll
  for (int c = 0; c < COUT_; c++) {
    float v = fmaf(acc[c] - stats[c], stats[64 + c], beta[c]);
    acc[c] = v;
    nv2 = fmaf(v, v, nv2);
  }
  float nv = sqrtf(nv2);
  float sv = (nv > LCLAMP_) ? (LCLAMP_ / nv) : 1.0f;  // logmap0(expmap0(v)) fused
  // ReLU in tangent space
  float nw2 = 0.f;
#pragma unroll
  for (int c = 0; c < COUT_; c++) {
    float w = fmaxf(acc[c] * sv, 0.f);
    acc[c] = w;
    nw2 = fmaf(w, w, nw2);
  }
  // final expmap0 + projx (the only real tanh)
  float nw = fmaxf(sqrtf(nw2), MINN_);
  float th = tanhf(nw);
  float se = th / nw;
  float clip = fminf(1.0f, MAXNORM_ / fmaxf(th, MINN_));
  float fs = se * clip;
  float4* op = (float4*)(out + (size_t)pix * 64);
#pragma unroll
  for (int c = 0; c < COUT_; c += 4)
    op[c >> 2] = make_float4(acc[c] * fs, acc[c + 1] * fs, acc[c + 2] * fs, acc[c + 3] * fs);
}

// ---------------------------------------------------------------------------
extern "C" void kernel_launch(void* const* d_in, const int* in_sizes, int n_in,
                              void* d_out, int out_size, void* d_ws, size_t ws_size,
                              hipStream_t stream) {
  const float* x     = (const float*)d_in[0];  // [16,3,224,224]
  const float* wgt   = (const float*)d_in[1];  // [3,3,3,64] HWIO
  const float* bias  = (const float*)d_in[2];  // [64]
  const float* gamma = (const float*)d_in[3];  // [64]
  const float* beta  = (const float*)d_in[4];  // [64]
  float* out = (float*)d_out;                  // [16,224,224,64]

  char* ws = (char*)d_ws;
  float4* u0p     = (float4*)ws;                                           // 13,075,456 B
  float*  partials = (float*)(ws + (size_t)NPAD_ * 16);                    //  1,605,632 B
  float*  stats    = (float*)(ws + (size_t)NPAD_ * 16 + (size_t)NBLK_ * 128 * 4); // 512 B

  hipLaunchKernelGGL(k0_transform, dim3((NPAD_ + 255) / 256), dim3(256), 0, stream, x, u0p);
  hipLaunchKernelGGL(k1_stats,     dim3(NBLK_),               dim3(256), 0, stream, u0p, wgt, bias, partials);
  hipLaunchKernelGGL(k2_finalize,  dim3(1),                   dim3(1024), 0, stream, partials, gamma, stats);
  hipLaunchKernelGGL(k3_final,     dim3(NBLK_),               dim3(256), 0, stream, u0p, wgt, bias, stats, beta, out);
}

// Round 2
// 396.207 us; speedup vs baseline: 1.0359x; 1.0359x over previous
//
#include <hip/hip_runtime.h>
#include <math.h>

#define B_ 16
#define H_ 224
#define W_ 224
#define HP_ 226
#define WP_ 226
#define CIN_ 3
#define COUT_ 64
#define NPIX_ (B_ * H_ * W_)      /* 802816 */
#define NPAD_ (B_ * HP_ * WP_)    /* 817216 */
#define NBLK_ (NPIX_ / 256)       /* 3136 */
#define MAXNORM_ 0.999f
#define MINN_ 1e-7f
#define TCL_ (1.0f - 1e-5f)
#define LCLAMP_ 3.8002012f        /* atanh(0.999) */
#define BN_EPS_ 1e-5f
#define NF_ ((float)NPIX_)

// ---------------------------------------------------------------------------
// K0: x (NCHW f32) -> u0p (padded NHWC4): u0 = logmap0(projx(x)) per pixel,
// zero halo ring (SAME padding happens in tangent space). ws is re-poisoned
// every launch, so the halo must be rewritten every call.
// ---------------------------------------------------------------------------
__global__ void k0_transform(const float* __restrict__ x, float4* __restrict__ u0p) {
  int idx = blockIdx.x * 256 + threadIdx.x;
  if (idx >= NPAD_) return;
  int b = idx / (HP_ * WP_);
  int r = idx % (HP_ * WP_);
  int yp = r / WP_, xp = r % WP_;
  float4 o = make_float4(0.f, 0.f, 0.f, 0.f);
  if (yp >= 1 && yp <= H_ && xp >= 1 && xp <= W_) {
    const float* xb = x + (size_t)b * (CIN_ * H_ * W_) + (size_t)(yp - 1) * W_ + (xp - 1);
    float v0 = xb[0];
    float v1 = xb[H_ * W_];
    float v2 = xb[2 * H_ * W_];
    // projx
    float n = sqrtf(fmaf(v0, v0, fmaf(v1, v1, v2 * v2)));
    float ncl = fmaxf(n, MINN_);
    float s = fminf(1.0f, MAXNORM_ / ncl);
    float p0 = v0 * s, p1 = v1 * s, p2 = v2 * s;
    // logmap0
    float np_ = fmaxf(sqrtf(fmaf(p0, p0, fmaf(p1, p1, p2 * p2))), MINN_);
    float t = fminf(np_, TCL_);
    float f = atanhf(t) / np_;
    o.x = p0 * f; o.y = p1 * f; o.z = p2 * f;
  }
  u0p[idx] = o;
}

// ---------------------------------------------------------------------------
// Shared conv: one thread = one output pixel, all 64 output channels in VGPRs.
// Weight indices are wave-uniform -> scalar (s_load) weight fetches; the FMA
// takes the weight as its single allowed SGPR operand. Then fuse
// logmap0(projx(expmap0(t))) == t * min(1, L/||t||).
// ---------------------------------------------------------------------------
__device__ __forceinline__ void conv_clamp(const float4* __restrict__ u0p,
                                           const float* __restrict__ wgt,
                                           const float* __restrict__ bias,
                                           int pix, float acc[COUT_]) {
  int b = pix / (H_ * W_);
  int r = pix % (H_ * W_);
  int y = r / W_, x = r % W_;
  const float4* base = u0p + ((size_t)b * HP_ + y) * WP_ + x;
#pragma unroll
  for (int c = 0; c < COUT_; c++) acc[c] = bias[c];
#pragma unroll
  for (int dy = 0; dy < 3; dy++) {
#pragma unroll
    for (int dx = 0; dx < 3; dx++) {
      float4 in = base[dy * WP_ + dx];
      const float* wp = wgt + (size_t)((dy * 3 + dx) * 3) * COUT_;  // HWIO layout
#pragma unroll
      for (int c = 0; c < COUT_; c++) acc[c] = fmaf(in.x, wp[c], acc[c]);
#pragma unroll
      for (int c = 0; c < COUT_; c++) acc[c] = fmaf(in.y, wp[COUT_ + c], acc[c]);
#pragma unroll
      for (int c = 0; c < COUT_; c++) acc[c] = fmaf(in.z, wp[2 * COUT_ + c], acc[c]);
    }
  }
  float n2 = 0.f;
#pragma unroll
  for (int c = 0; c < COUT_; c++) n2 = fmaf(acc[c], acc[c], n2);
  float n = sqrtf(n2);
  float s = (n > LCLAMP_) ? (LCLAMP_ / n) : 1.0f;
#pragma unroll
  for (int c = 0; c < COUT_; c++) acc[c] *= s;
}

// ---------------------------------------------------------------------------
// K1: conv + clamp, then per-wave channel-ownership butterfly (all-static
// register indices, no scratch spill): after 6 xor-fold steps lane l holds the
// wave total for channel l (sum and sumsq). Block-combine in LDS, write one
// 128-float partial row per block.
// __launch_bounds__(256,1): needs ~190 live VGPRs (s[64]+q[64]+conv overhead);
// default heuristic spilled everything at 48 VGPRs (R1: WRITE_SIZE 2.2x ideal).
// ---------------------------------------------------------------------------
__global__ void __launch_bounds__(256, 1)
k1_stats(const float4* __restrict__ u0p, const float* __restrict__ wgt,
         const float* __restrict__ bias, float* __restrict__ partials) {
  int pix = blockIdx.x * 256 + threadIdx.x;
  float s[COUT_];
  conv_clamp(u0p, wgt, bias, pix, s);
  float q[COUT_];
#pragma unroll
  for (int c = 0; c < COUT_; c++) q[c] = s[c] * s[c];
  int lane = threadIdx.x & 63;
#pragma unroll
  for (int k = 0; k < 6; k++) {
    int bit = (lane >> k) & 1;
#pragma unroll
    for (int j = 0; j < (64 >> k); j += 2) {
      float a0 = s[j]     + __shfl_xor(s[j],     1 << k, 64);
      float a1 = s[j + 1] + __shfl_xor(s[j + 1], 1 << k, 64);
      s[j >> 1] = bit ? a1 : a0;
      float b0 = q[j]     + __shfl_xor(q[j],     1 << k, 64);
      float b1 = q[j + 1] + __shfl_xor(q[j + 1], 1 << k, 64);
      q[j >> 1] = bit ? b1 : b0;
    }
  }
  __shared__ float red[512];
  int wid = threadIdx.x >> 6;
  red[wid * 64 + lane] = s[0];
  red[256 + wid * 64 + lane] = q[0];
  __syncthreads();
  int tid = threadIdx.x;
  if (tid < 128) {
    int off = (tid < 64) ? 0 : (256 - 64);
    float tot = red[off + tid] + red[off + tid + 64] + red[off + tid + 128] + red[off + tid + 192];
    // layout: partials[blk*128 + c] = sum_c  ;  partials[blk*128 + 64 + c] = sumsq_c
    partials[(size_t)blockIdx.x * 128 + tid] = tot;
  }
}

// ---------------------------------------------------------------------------
// K2: reduce 3136 x 128 partials -> mean[c], rstd*gamma[c]. One 1024-thread
// block, float4 chunked 32-way so ~8 loads are in flight per thread.
// ---------------------------------------------------------------------------
__global__ void k2_finalize(const float* __restrict__ partials, const float* __restrict__ gamma,
                            float* __restrict__ stats) {
  __shared__ float lds[32 * 128 + 128];
  int tid = threadIdx.x;  // 1024 threads
  int chunk = tid >> 5, qi = tid & 31;
  const float4* p4 = (const float4*)partials;
  float4 a = make_float4(0.f, 0.f, 0.f, 0.f);
#pragma unroll 7
  for (int i = chunk; i < NBLK_; i += 32) {
    float4 v = p4[(size_t)i * 32 + qi];
    a.x += v.x; a.y += v.y; a.z += v.z; a.w += v.w;
  }
  lds[chunk * 128 + qi * 4 + 0] = a.x;
  lds[chunk * 128 + qi * 4 + 1] = a.y;
  lds[chunk * 128 + qi * 4 + 2] = a.z;
  lds[chunk * 128 + qi * 4 + 3] = a.w;
  __syncthreads();
  if (tid < 128) {
    float tot = 0.f;
#pragma unroll
    for (int ch = 0; ch < 32; ch++) tot += lds[ch * 128 + tid];
    lds[32 * 128 + tid] = tot;
  }
  __syncthreads();
  if (tid < 64) {
    float mean = lds[32 * 128 + tid] / NF_;
    float msq  = lds[32 * 128 + 64 + tid] / NF_;
    float var = msq - mean * mean;            // jnp.var (ddof=0)
    float rstdg = gamma[tid] / sqrtf(var + BN_EPS_);
    stats[tid] = mean;
    stats[64 + tid] = rstdg;
  }
}

// ---------------------------------------------------------------------------
// K3: conv + clamp + BN affine + clamp + ReLU + real expmap0 (+projx) + store.
// __launch_bounds__(256,2): cap 256 VGPRs, expect ~120 actual -> 4 waves/SIMD,
// no spill (R1 showed 48 VGPRs + 250 MB scratch write traffic without this).
// ---------------------------------------------------------------------------
__global__ void __launch_bounds__(256, 2)
k3_final(const float4* __restrict__ u0p, const float* __restrict__ wgt,
         const float* __restrict__ bias, const float* __restrict__ stats,
         const float* __restrict__ beta, float* __restrict__ out) {
  int pix = blockIdx.x * 256 + threadIdx.x;
  float acc[COUT_];
  conv_clamp(u0p, wgt, bias, pix, acc);
  // BN:  v = (u2 - mean) * (rstd*gamma) + beta    (stats indices wave-uniform)
  float nv2 = 0.f;
#pragma unroll
  for (int c = 0; c < COUT_; c++) {
    float v = fmaf(acc[c] - stats[c], stats[64 + c], beta[c]);
    acc[c] = v;
    nv2 = fmaf(v, v, nv2);
  }
  float nv = sqrtf(nv2);
  float sv = (nv > LCLAMP_) ? (LCLAMP_ / nv) : 1.0f;  // logmap0(expmap0(v)) fused
  // ReLU in tangent space
  float nw2 = 0.f;
#pragma unroll
  for (int c = 0; c < COUT_; c++) {
    float w = fmaxf(acc[c] * sv, 0.f);
    acc[c] = w;
    nw2 = fmaf(w, w, nw2);
  }
  // final expmap0 + projx (the only real tanh)
  float nw = fmaxf(sqrtf(nw2), MINN_);
  float th = tanhf(nw);
  float se = th / nw;
  float clip = fminf(1.0f, MAXNORM_ / fmaxf(th, MINN_));
  float fs = se * clip;
  float4* op = (float4*)(out + (size_t)pix * 64);
#pragma unroll
  for (int c = 0; c < COUT_; c += 4)
    op[c >> 2] = make_float4(acc[c] * fs, acc[c + 1] * fs, acc[c + 2] * fs, acc[c + 3] * fs);
}

// ---------------------------------------------------------------------------
extern "C" void kernel_launch(void* const* d_in, const int* in_sizes, int n_in,
                              void* d_out, int out_size, void* d_ws, size_t ws_size,
                              hipStream_t stream) {
  const float* x     = (const float*)d_in[0];  // [16,3,224,224]
  const float* wgt   = (const float*)d_in[1];  // [3,3,3,64] HWIO
  const float* bias  = (const float*)d_in[2];  // [64]
  const float* gamma = (const float*)d_in[3];  // [64]
  const float* beta  = (const float*)d_in[4];  // [64]
  float* out = (float*)d_out;                  // [16,224,224,64]

  char* ws = (char*)d_ws;
  float4* u0p     = (float4*)ws;                                           // 13,075,456 B
  float*  partials = (float*)(ws + (size_t)NPAD_ * 16);                    //  1,605,632 B
  float*  stats    = (float*)(ws + (size_t)NPAD_ * 16 + (size_t)NBLK_ * 128 * 4); // 512 B

  hipLaunchKernelGGL(k0_transform, dim3((NPAD_ + 255) / 256), dim3(256), 0, stream, x, u0p);
  hipLaunchKernelGGL(k1_stats,     dim3(NBLK_),               dim3(256), 0, stream, u0p, wgt, bias, partials);
  hipLaunchKernelGGL(k2_finalize,  dim3(1),                   dim3(1024), 0, stream, partials, gamma, stats);
  hipLaunchKernelGGL(k3_final,     dim3(NBLK_),               dim3(256), 0, stream, u0p, wgt, bias, stats, beta, out);
}

// Round 3
// 384.713 us; speedup vs baseline: 1.0669x; 1.0299x over previous
//
#include <hip/hip_runtime.h>
#include <math.h>

#define B_ 16
#define H_ 224
#define W_ 224
#define HP_ 226
#define WP_ 226
#define CIN_ 3
#define COUT_ 64
#define NPIX_ (B_ * H_ * W_)      /* 802816 */
#define NPAD_ (B_ * HP_ * WP_)    /* 817216 */
#define NBLK_ (NPIX_ / 256)       /* 3136 */
#define MAXNORM_ 0.999f
#define MINN_ 1e-7f
#define TCL_ (1.0f - 1e-5f)
#define LCLAMP_ 3.8002012f        /* atanh(0.999) */
#define BN_EPS_ 1e-5f
#define NF_ ((float)NPIX_)

typedef float v4f __attribute__((ext_vector_type(4)));

// 64 accumulators as 16 NAMED vector members. Never indexed with a variable:
// all access is macro-expanded constant member names -> first-class SSA values,
// immune to the SROA-before-unroll alloca trap that left R1/R2 at 48 VGPRs with
// 250+ MB of scratch spill traffic (WRITE_SIZE 2.5x ideal, VGPR_Count frozen).
struct Acc {
  v4f v0, v1, v2, v3, v4, v5, v6, v7, v8, v9, v10, v11, v12, v13, v14, v15;
};

#define EACH16(X) X(0) X(1) X(2) X(3) X(4) X(5) X(6) X(7) \
                  X(8) X(9) X(10) X(11) X(12) X(13) X(14) X(15)

// ---------------------------------------------------------------------------
// K0: x (NCHW f32) -> u0p (padded NHWC4): u0 = logmap0(projx(x)) per pixel,
// zero halo ring (SAME padding happens in tangent space). ws is re-poisoned
// every launch, so the halo must be rewritten every call.
// ---------------------------------------------------------------------------
__global__ void k0_transform(const float* __restrict__ x, float4* __restrict__ u0p) {
  int idx = blockIdx.x * 256 + threadIdx.x;
  if (idx >= NPAD_) return;
  int b = idx / (HP_ * WP_);
  int r = idx % (HP_ * WP_);
  int yp = r / WP_, xp = r % WP_;
  float4 o = make_float4(0.f, 0.f, 0.f, 0.f);
  if (yp >= 1 && yp <= H_ && xp >= 1 && xp <= W_) {
    const float* xb = x + (size_t)b * (CIN_ * H_ * W_) + (size_t)(yp - 1) * W_ + (xp - 1);
    float v0 = xb[0];
    float v1 = xb[H_ * W_];
    float v2 = xb[2 * H_ * W_];
    // projx
    float n = sqrtf(fmaf(v0, v0, fmaf(v1, v1, v2 * v2)));
    float ncl = fmaxf(n, MINN_);
    float s = fminf(1.0f, MAXNORM_ / ncl);
    float p0 = v0 * s, p1 = v1 * s, p2 = v2 * s;
    // logmap0
    float np_ = fmaxf(sqrtf(fmaf(p0, p0, fmaf(p1, p1, p2 * p2))), MINN_);
    float t = fminf(np_, TCL_);
    float f = atanhf(t) / np_;
    o.x = p0 * f; o.y = p1 * f; o.z = p2 * f;
  }
  u0p[idx] = o;
}

// ---------------------------------------------------------------------------
// Shared conv: one thread = one output pixel, all 64 output channels live in
// 16 named v4f registers. Weight addresses are wave-uniform -> scalar loads.
// Fused logmap0(projx(expmap0(t))) == t * min(1, L/||t||).
// ---------------------------------------------------------------------------
__device__ __forceinline__ void conv_clamp(const float4* __restrict__ u0p,
                                           const float* __restrict__ wgt,
                                           const float* __restrict__ bias,
                                           int pix, Acc& a) {
  int b = pix / (H_ * W_);
  int r = pix % (H_ * W_);
  int y = r / W_, x = r % W_;
  const float4* base = u0p + ((size_t)b * HP_ + y) * WP_ + x;
  const v4f* b4 = (const v4f*)bias;
#define INIT(i) a.v##i = b4[i];
  EACH16(INIT)
#undef INIT
#define FMA_X(i) a.v##i += in.x * wp[i];
#define FMA_Y(i) a.v##i += in.y * wp[16 + i];
#define FMA_Z(i) a.v##i += in.z * wp[32 + i];
#define TAP(t) { float4 in = base[((t) / 3) * WP_ + ((t) % 3)];              \
                 const v4f* wp = (const v4f*)(wgt + (t) * 3 * COUT_);        \
                 EACH16(FMA_X) EACH16(FMA_Y) EACH16(FMA_Z) }
  TAP(0) TAP(1) TAP(2) TAP(3) TAP(4) TAP(5) TAP(6) TAP(7) TAP(8)
#undef TAP
#undef FMA_X
#undef FMA_Y
#undef FMA_Z
  v4f s2 = (v4f)0.0f;
#define SQ(i) s2 += a.v##i * a.v##i;
  EACH16(SQ)
#undef SQ
  float n2 = s2.x + s2.y + s2.z + s2.w;
  float n = sqrtf(n2);
  float sc = (n > LCLAMP_) ? (LCLAMP_ / n) : 1.0f;
#define SCL(i) a.v##i *= sc;
  EACH16(SCL)
#undef SCL
}

// ---------------------------------------------------------------------------
// Channel-ownership butterfly over named vectors: after 6 fold steps, lane l
// holds the 64-lane total of channel l. Compaction is __builtin_shufflevector
// (constant masks, pure register ops); only the adds cross lanes (126 DS ops).
// Same dataflow as the R1-verified array butterfly.
// ---------------------------------------------------------------------------
__device__ __forceinline__ v4f vshfl_xor(v4f v, int m) {
  v4f r;
  r.x = __shfl_xor(v.x, m, 64);
  r.y = __shfl_xor(v.y, m, 64);
  r.z = __shfl_xor(v.z, m, 64);
  r.w = __shfl_xor(v.w, m, 64);
  return r;
}
__device__ __forceinline__ v4f pick_ev(bool b, v4f lo, v4f hi) {
  v4f e = __builtin_shufflevector(lo, hi, 0, 2, 4, 6);
  v4f o = __builtin_shufflevector(lo, hi, 1, 3, 5, 7);
  return b ? o : e;
}

__device__ __forceinline__ float fold64(const Acc& a, int lane) {
  bool b0 = lane & 1, b1 = lane & 2, b2 = lane & 4;
  bool b3 = lane & 8, b4 = lane & 16, b5 = lane & 32;
  // step 0: xor 1, 64ch -> 32ch
#define F0(i) v4f t##i = a.v##i + vshfl_xor(a.v##i, 1);
  EACH16(F0)
#undef F0
  v4f u0 = pick_ev(b0, t0, t1),   u1 = pick_ev(b0, t2, t3);
  v4f u2 = pick_ev(b0, t4, t5),   u3 = pick_ev(b0, t6, t7);
  v4f u4 = pick_ev(b0, t8, t9),   u5 = pick_ev(b0, t10, t11);
  v4f u6 = pick_ev(b0, t12, t13), u7 = pick_ev(b0, t14, t15);
  // step 1: xor 2, 32 -> 16
  v4f s0 = u0 + vshfl_xor(u0, 2), s1 = u1 + vshfl_xor(u1, 2);
  v4f s2 = u2 + vshfl_xor(u2, 2), s3 = u3 + vshfl_xor(u3, 2);
  v4f s4 = u4 + vshfl_xor(u4, 2), s5 = u5 + vshfl_xor(u5, 2);
  v4f s6 = u6 + vshfl_xor(u6, 2), s7 = u7 + vshfl_xor(u7, 2);
  v4f w0 = pick_ev(b1, s0, s1), w1 = pick_ev(b1, s2, s3);
  v4f w2 = pick_ev(b1, s4, s5), w3 = pick_ev(b1, s6, s7);
  // step 2: xor 4, 16 -> 8
  v4f p0 = w0 + vshfl_xor(w0, 4), p1 = w1 + vshfl_xor(w1, 4);
  v4f p2 = w2 + vshfl_xor(w2, 4), p3 = w3 + vshfl_xor(w3, 4);
  v4f y0 = pick_ev(b2, p0, p1), y1 = pick_ev(b2, p2, p3);
  // step 3: xor 8, 8 -> 4
  v4f z0 = y0 + vshfl_xor(y0, 8), z1 = y1 + vshfl_xor(y1, 8);
  v4f m0 = pick_ev(b3, z0, z1);
  // step 4: xor 16, 4 -> 2
  v4f n0 = m0 + vshfl_xor(m0, 16);
  float c0 = b4 ? n0.y : n0.x;
  float c1 = b4 ? n0.w : n0.z;
  // step 5: xor 32, 2 -> 1
  float d0 = c0 + __shfl_xor(c0, 32, 64);
  float d1 = c1 + __shfl_xor(c1, 32, 64);
  return b5 ? d1 : d0;
}

// ---------------------------------------------------------------------------
// K1: conv + clamp + butterfly -> one 128-float partial row per block.
// (256,1): fold needs ~200 live VGPRs (sum-set + sq-set + temps).
// ---------------------------------------------------------------------------
__global__ void __launch_bounds__(256, 1)
k1_stats(const float4* __restrict__ u0p, const float* __restrict__ wgt,
         const float* __restrict__ bias, float* __restrict__ partials) {
  int pix = blockIdx.x * 256 + threadIdx.x;
  Acc a;
  conv_clamp(u0p, wgt, bias, pix, a);
  Acc q;
#define SQV(i) q.v##i = a.v##i * a.v##i;
  EACH16(SQV)
#undef SQV
  int lane = threadIdx.x & 63;
  float s_tot = fold64(a, lane);
  float q_tot = fold64(q, lane);
  __shared__ float red[512];
  int wid = threadIdx.x >> 6;
  red[wid * 64 + lane] = s_tot;
  red[256 + wid * 64 + lane] = q_tot;
  __syncthreads();
  int tid = threadIdx.x;
  if (tid < 128) {
    int off = (tid < 64) ? 0 : (256 - 64);
    float tot = red[off + tid] + red[off + tid + 64] + red[off + tid + 128] + red[off + tid + 192];
    // partials[blk*128 + c] = sum_c ; partials[blk*128 + 64 + c] = sumsq_c
    partials[(size_t)blockIdx.x * 128 + tid] = tot;
  }
}

// ---------------------------------------------------------------------------
// K2: reduce 3136 x 128 partials -> mean[c], rstd*gamma[c]. One 1024-thread
// block, float4 chunked 32-way so ~8 loads are in flight per thread.
// ---------------------------------------------------------------------------
__global__ void k2_finalize(const float* __restrict__ partials, const float* __restrict__ gamma,
                            float* __restrict__ stats) {
  __shared__ float lds[32 * 128 + 128];
  int tid = threadIdx.x;  // 1024 threads
  int chunk = tid >> 5, qi = tid & 31;
  const float4* p4 = (const float4*)partials;
  float4 a = make_float4(0.f, 0.f, 0.f, 0.f);
#pragma unroll 7
  for (int i = chunk; i < NBLK_; i += 32) {
    float4 v = p4[(size_t)i * 32 + qi];
    a.x += v.x; a.y += v.y; a.z += v.z; a.w += v.w;
  }
  lds[chunk * 128 + qi * 4 + 0] = a.x;
  lds[chunk * 128 + qi * 4 + 1] = a.y;
  lds[chunk * 128 + qi * 4 + 2] = a.z;
  lds[chunk * 128 + qi * 4 + 3] = a.w;
  __syncthreads();
  if (tid < 128) {
    float tot = 0.f;
#pragma unroll
    for (int ch = 0; ch < 32; ch++) tot += lds[ch * 128 + tid];
    lds[32 * 128 + tid] = tot;
  }
  __syncthreads();
  if (tid < 64) {
    float mean = lds[32 * 128 + tid] / NF_;
    float msq  = lds[32 * 128 + 64 + tid] / NF_;
    float var = msq - mean * mean;            // jnp.var (ddof=0)
    float rstdg = gamma[tid] / sqrtf(var + BN_EPS_);
    stats[tid] = mean;
    stats[64 + tid] = rstdg;
  }
}

// ---------------------------------------------------------------------------
// K3: conv + clamp + BN affine + clamp + ReLU + real expmap0 (+projx) + store.
// ---------------------------------------------------------------------------
__global__ void __launch_bounds__(256, 2)
k3_final(const float4* __restrict__ u0p, const float* __restrict__ wgt,
         const float* __restrict__ bias, const float* __restrict__ stats,
         const float* __restrict__ beta, float* __restrict__ out) {
  int pix = blockIdx.x * 256 + threadIdx.x;
  Acc a;
  conv_clamp(u0p, wgt, bias, pix, a);
  const v4f* mean4 = (const v4f*)stats;
  const v4f* rg4   = (const v4f*)(stats + 64);
  const v4f* beta4 = (const v4f*)beta;
  v4f s2 = (v4f)0.0f;
#define BN(i) { a.v##i = (a.v##i - mean4[i]) * rg4[i] + beta4[i]; s2 += a.v##i * a.v##i; }
  EACH16(BN)
#undef BN
  float nv2 = s2.x + s2.y + s2.z + s2.w;
  float nv = sqrtf(nv2);
  float sv = (nv > LCLAMP_) ? (LCLAMP_ / nv) : 1.0f;  // logmap0(expmap0(v)) fused
  // ReLU in tangent space
  v4f z2 = (v4f)0.0f;
#define RELU(i) { v4f r = a.v##i * sv;                                      \
                  r.x = fmaxf(r.x, 0.f); r.y = fmaxf(r.y, 0.f);             \
                  r.z = fmaxf(r.z, 0.f); r.w = fmaxf(r.w, 0.f);             \
                  a.v##i = r; z2 += r * r; }
  EACH16(RELU)
#undef RELU
  float nw2 = z2.x + z2.y + z2.z + z2.w;
  // final expmap0 + projx (the only real tanh)
  float nw = fmaxf(sqrtf(nw2), MINN_);
  float th = tanhf(nw);
  float se = th / nw;
  float clip = fminf(1.0f, MAXNORM_ / fmaxf(th, MINN_));
  float fs = se * clip;
  v4f* op = (v4f*)(out + (size_t)pix * 64);
#define STORE(i) op[i] = a.v##i * fs;
  EACH16(STORE)
#undef STORE
}

// ---------------------------------------------------------------------------
extern "C" void kernel_launch(void* const* d_in, const int* in_sizes, int n_in,
                              void* d_out, int out_size, void* d_ws, size_t ws_size,
                              hipStream_t stream) {
  const float* x     = (const float*)d_in[0];  // [16,3,224,224]
  const float* wgt   = (const float*)d_in[1];  // [3,3,3,64] HWIO
  const float* bias  = (const float*)d_in[2];  // [64]
  const float* gamma = (const float*)d_in[3];  // [64]
  const float* beta  = (const float*)d_in[4];  // [64]
  float* out = (float*)d_out;                  // [16,224,224,64]

  char* ws = (char*)d_ws;
  float4* u0p      = (float4*)ws;                                           // 13,075,456 B
  float*  partials = (float*)(ws + (size_t)NPAD_ * 16);                     //  1,605,632 B
  float*  stats    = (float*)(ws + (size_t)NPAD_ * 16 + (size_t)NBLK_ * 128 * 4); // 512 B

  hipLaunchKernelGGL(k0_transform, dim3((NPAD_ + 255) / 256), dim3(256), 0, stream, x, u0p);
  hipLaunchKernelGGL(k1_stats,     dim3(NBLK_),               dim3(256), 0, stream, u0p, wgt, bias, partials);
  hipLaunchKernelGGL(k2_finalize,  dim3(1),                   dim3(1024), 0, stream, partials, gamma, stats);
  hipLaunchKernelGGL(k3_final,     dim3(NBLK_),               dim3(256), 0, stream, u0p, wgt, bias, stats, beta, out);
}